// Round 5
// baseline (31.684 us; speedup 1.0000x reference)
//
#include <hip/hip_runtime.h>

#define BB 16
#define NL 60
#define NA 3
#define NC 80

// blocks per batch: 17(s0)+5(s1)+2(s2) cell blocks (4 cells/thread) + 3 target blocks
#define NBX0C 17
#define NBX1C 5
#define NBX2C 2
#define NBXC  (NBX0C+NBX1C+NBX2C)   // 24
#define NBX   (NBXC+3)              // 27
#define TOTAL_BLOCKS (NBX*BB)       // 432

// ws layout: 5 float accumulator slots, 256 B apart (distinct cache lines/channels),
// then a counter. memset 1536 B each call bootstraps past the 0xAA poison.
#define SLOT_STRIDE 64              // floats (256 B)

__device__ __constant__ float d_AW[9] = {12.f,19.f,40.f,36.f,76.f,72.f,142.f,192.f,459.f};
__device__ __constant__ float d_AH[9] = {16.f,36.f,28.f,75.f,55.f,146.f,110.f,243.f,401.f};

__device__ __forceinline__ float sig_pos(float v){ return __fdividef(1.0f, 1.0f + __expf(-v)); }
__device__ __forceinline__ float sig_neg(float v){ return __fdividef(1.0f, 1.0f + __expf(v)); }
__device__ __forceinline__ float bcef(float p, float t){
    float lp  = __logf(fmaxf(p, 1e-12f));
    float l1p = __logf(1.0f - fminf(p, 1.0f - 1e-7f));
    return -(t*lp + (1.0f - t)*l1p);
}

// ---- issue the channel loads EARLY (before prep+barrier) ----
template<int SID>
__device__ __forceinline__ bool cell_load(const float* __restrict__ raw, int xoff, int b, int tid,
        int &a, int &rembase, int &nc,
        float (&cx)[4], float (&cy)[4], float (&cw)[4], float (&ch)[4], float (&co)[4])
{
    constexpr int F  = (SID==0)?76:(SID==1)?38:19;
    constexpr int FF = F*F;
    int t = xoff*256 + tid;
    if (SID < 2){
        constexpr int NT = 3*FF/4;           // FF divisible by 4 for s0/s1
        if (t >= NT) return false;
        a = t / (FF/4);
        rembase = 4*t - a*FF;
        nc = 4;
        const float* base = raw + ((size_t)(b*(NA*85) + a*85))*FF + rembase;
        float4 q0 = *reinterpret_cast<const float4*>(base);
        float4 q1 = *reinterpret_cast<const float4*>(base +   (size_t)FF);
        float4 q2 = *reinterpret_cast<const float4*>(base + 2*(size_t)FF);
        float4 q3 = *reinterpret_cast<const float4*>(base + 3*(size_t)FF);
        float4 q4 = *reinterpret_cast<const float4*>(base + 4*(size_t)FF);
        cx[0]=q0.x; cx[1]=q0.y; cx[2]=q0.z; cx[3]=q0.w;
        cy[0]=q1.x; cy[1]=q1.y; cy[2]=q1.z; cy[3]=q1.w;
        cw[0]=q2.x; cw[1]=q2.y; cw[2]=q2.z; cw[3]=q2.w;
        ch[0]=q3.x; ch[1]=q3.y; ch[2]=q3.z; ch[3]=q3.w;
        co[0]=q4.x; co[1]=q4.y; co[2]=q4.z; co[3]=q4.w;
    } else {
        constexpr int GPA = (FF+3)/4;        // 91 groups per anchor (361 cells)
        if (t >= 3*GPA) return false;
        a = t / GPA;
        int k = t - a*GPA;
        rembase = 4*k;
        nc = (FF - rembase < 4) ? (FF - rembase) : 4;
        const float* base = raw + ((size_t)(b*(NA*85) + a*85))*FF + rembase;
        #pragma unroll
        for (int c=0;c<4;c++){
            bool v = c < nc;
            cx[c] = v ? base[c]              : 0.f;
            cy[c] = v ? base[(size_t)FF+c]   : 0.f;
            cw[c] = v ? base[2*(size_t)FF+c] : 0.f;
            ch[c] = v ? base[3*(size_t)FF+c] : 0.f;
            co[c] = v ? base[4*(size_t)FF+c] : 0.f;
        }
    }
    return true;
}

template<int SID>
__device__ __forceinline__ void cell_compute(int a, int rembase, int nc,
        const float (&cx)[4], const float (&cy)[4], const float (&cw)[4],
        const float (&ch)[4], const float (&co)[4],
        const float4* s_bxc, const float* s_at3c, int nbx,
        const int* s_used, int nuse,
        float &lob, float &l2)
{
    constexpr int   F   = (SID==0)?76:(SID==1)?38:19;
    constexpr int   FF  = F*F;
    constexpr float RST = (SID==0)?0.125f:(SID==1)?0.0625f:0.03125f;
    float aw = d_AW[SID*3+a]*RST, ah = d_AH[SID*3+a]*RST;
    // only bounds + thresholds live through the label loop (register-lean)
    float plox[4],phix[4],ploy[4],phiy[4],ap3[4];
    #pragma unroll
    for (int c=0;c<4;c++){
        int cel = rembase + c;
        int j = cel / F;                 // compile-time divisor
        int i = cel - j*F;
        float x = sig_pos(cx[c]), y = sig_pos(cy[c]);
        float pw = __expf(cw[c])*aw, ph = __expf(ch[c])*ah;
        float px = x + (float)i, py = y + (float)j;
        float hx = 0.5f*pw, hy = 0.5f*ph;
        plox[c]=px-hx; phix[c]=px+hx; ploy[c]=py-hy; phiy[c]=py+hy;
        ap3[c]=pw*ph*(1.0f/3.0f);
    }
    bool skip0=false, skip1=false, skip2=false, skip3=false;
    #pragma unroll 2
    for (int l=0;l<nbx;l++){             // compacted: valid labels only
        float4 bb = s_bxc[l];
        float thr = s_at3c[l];
        float iw0 = fminf(phix[0],bb.y)-fmaxf(plox[0],bb.x);
        float ih0 = fminf(phiy[0],bb.w)-fmaxf(ploy[0],bb.z);
        float iw1 = fminf(phix[1],bb.y)-fmaxf(plox[1],bb.x);
        float ih1 = fminf(phiy[1],bb.w)-fmaxf(ploy[1],bb.z);
        float iw2 = fminf(phix[2],bb.y)-fmaxf(plox[2],bb.x);
        float ih2 = fminf(phiy[2],bb.w)-fmaxf(ploy[2],bb.z);
        float iw3 = fminf(phix[3],bb.y)-fmaxf(plox[3],bb.x);
        float ih3 = fminf(phiy[3],bb.w)-fmaxf(ploy[3],bb.z);
        skip0 = skip0 || (fmaxf(iw0,0.f)*fmaxf(ih0,0.f) > ap3[0]+thr);
        skip1 = skip1 || (fmaxf(iw1,0.f)*fmaxf(ih1,0.f) > ap3[1]+thr);
        skip2 = skip2 || (fmaxf(iw2,0.f)*fmaxf(ih2,0.f) > ap3[2]+thr);
        skip3 = skip3 || (fmaxf(iw3,0.f)*fmaxf(ih3,0.f) > ap3[3]+thr);
    }
    int cellbase = a*FF + rembase;
    for (int k=0;k<nuse;k++){
        int uc = s_used[k];
        skip0 = skip0 || (uc==cellbase);
        skip1 = skip1 || (uc==cellbase+1);
        skip2 = skip2 || (uc==cellbase+2);
        skip3 = skip3 || (uc==cellbase+3);
    }
    // obj loss only now (keeps lobv/l2v out of the loop's live set)
    #pragma unroll
    for (int c=0;c<4;c++){
        bool sk = (c==0)?skip0:(c==1)?skip1:(c==2)?skip2:skip3;
        if (c < nc && !sk){
            float snb = sig_neg(co[c]);
            lob += -__logf(fmaxf(snb,1e-7f));
            float ob = 1.0f - snb;
            l2 += ob*ob;
        }
    }
}

template<int SID>
__device__ __forceinline__ void target_pass(const float* __restrict__ raw, int b, int tid,
        const int* s_code, const float (*s_tv)[5],
        float &lxy, float &lwh, float &lob, float &lcl, float &l2)
{
    constexpr int F  = (SID==0)?76:(SID==1)?38:19;
    constexpr int FF = F*F;
    const int wv = tid>>6, lane = tid&63;
    int mycode = (lane < NL) ? s_code[lane] : -1;
    for (int l=wv; l<NL; l+=4){                  // wave-uniform l
        int cd = s_code[l];
        if (cd < 0) continue;
        int tcell = cd & 0xFFFFF;
        bool match = (mycode >= 0) && ((mycode & 0xFFFFF) == tcell);
        unsigned long long mask = __ballot(match);
        int last = 63 - __clzll(mask);
        if (last != l) continue;                 // single owner per cell
        unsigned long long cm0=0ull, cm1=0ull, mm=mask;
        while (mm){
            int q = __ffsll((unsigned long long)mm) - 1;
            mm &= mm - 1;
            int cc = s_code[q] >> 20;
            if (cc < 64) cm0 |= 1ull<<cc; else cm1 |= 1ull<<(cc-64);
        }
        int aa = tcell / FF, rr = tcell - aa*FF;
        const float* cb = raw + ((size_t)(b*(NA*85) + aa*85))*FF + rr;
        // hoist all loads before the transcendental block
        float p1l = cb[(size_t)(5+lane)*FF];
        float p2l = (lane < 16) ? cb[(size_t)(69+lane)*FF] : 0.f;
        float e0=0.f,e1=0.f,e2=0.f,e3=0.f,e4=0.f;
        if (lane == 0){ e0=cb[0]; e1=cb[(size_t)FF]; e2=cb[2*(size_t)FF];
                        e3=cb[3*(size_t)FF]; e4=cb[4*(size_t)FF]; }
        float p1 = sig_pos(p1l);
        float t1v = (((cm0>>lane)&1ull)!=0ull) ? 1.f : 0.f;
        lcl += bcef(p1, t1v);
        float d1 = p1 - t1v; l2 += d1*d1;
        if (lane < 16){
            float p2 = sig_pos(p2l);
            float t2v = (((cm1>>lane)&1ull)!=0ull) ? 1.f : 0.f;
            lcl += bcef(p2, t2v);
            float d2 = p2 - t2v; l2 += d2*d2;
        }
        if (lane == 0){
            float xx=sig_pos(e0), yy=sig_pos(e1), ob=sig_pos(e4);
            float t0=s_tv[l][0], t1=s_tv[l][1], t2=s_tv[l][2], t3=s_tv[l][3], sc=s_tv[l][4];
            lxy += sc*sc*(bcef(xx,t0)+bcef(yy,t1));
            float d0=(e2-t2)*sc, dd=(e3-t3)*sc;
            lwh += 0.5f*(d0*d0+dd*dd);
            lob += -__logf(fmaxf(ob,1e-12f));
            float dx=xx-t0, dy=yy-t1, dob=ob-1.f;
            l2  += dx*dx+dy*dy+d0*d0+dd*dd+dob*dob;
        }
    }
}

__global__ __launch_bounds__(256) void fused_kernel(
        const float* __restrict__ x0, const float* __restrict__ x1,
        const float* __restrict__ x2, const float* __restrict__ labels,
        float* __restrict__ acc, unsigned* __restrict__ cnt,
        float* __restrict__ out)
{
    __shared__ float4 s_bxc[NL];     // compacted valid-label boxes
    __shared__ float  s_at3c[NL];    // compacted area/3
    __shared__ int    s_code[NL];    // original-index cell|class codes
    __shared__ float  s_tv[NL][5];
    __shared__ int    s_used[NL];
    __shared__ int    s_nuse, s_nbx;
    __shared__ float  red[5][4];

    const int tid = threadIdx.x;
    const int bxi = blockIdx.x;
    const int b   = blockIdx.y;

    int sid, xoff, tgtblk;
    if      (bxi < NBX0C)       { sid = 0; xoff = bxi;               tgtblk = 0; }
    else if (bxi < NBX0C+NBX1C) { sid = 1; xoff = bxi-NBX0C;         tgtblk = 0; }
    else if (bxi < NBXC)        { sid = 2; xoff = bxi-(NBX0C+NBX1C); tgtblk = 0; }
    else                        { sid = bxi-NBXC; xoff = 0;          tgtblk = 1; }

    const float RSTv = (sid==0)?0.125f:(sid==1)?0.0625f:0.03125f;
    const int   F    = (sid==0)?76:(sid==1)?38:19;
    const int   FF   = F*F;
    const float* raw = (sid==0)?x0:(sid==1)?x1:x2;

    // ---- issue cell loads before prep so latency hides under prep+barrier ----
    float cx[4],cy[4],cw[4],chn[4],co[4];
    int a=0, rembase=0, nc=0;
    bool active=false;
    if (!tgtblk){
        if      (sid==0) active = cell_load<0>(raw,xoff,b,tid,a,rembase,nc,cx,cy,cw,chn,co);
        else if (sid==1) active = cell_load<1>(raw,xoff,b,tid,a,rembase,nc,cx,cy,cw,chn,co);
        else             active = cell_load<2>(raw,xoff,b,tid,a,rembase,nc,cx,cy,cw,chn,co);
    }

    if (tid == 0){ s_nuse = 0; s_nbx = 0; }
    __syncthreads();

    // ---- per-block label prep (this block's scale) ----
    if (tid < NL){
        const float* lb = labels + ((size_t)b*NL + tid)*5;
        float x1f=lb[0], y1f=lb[1], x2f=lb[2], y2f=lb[3], cl=lb[4];
        bool valid = (x1f+y1f+x2f+y2f+cl) > 0.0f;
        float tx=(x1f+x2f)*0.5f*RSTv, ty=(y1f+y2f)*0.5f*RSTv;
        float tw=(x2f-x1f)*RSTv, th=(y2f-y1f)*RSTv;
        float at=tw*th;
        float best=-1.0f; int bi=0;
        #pragma unroll
        for (int k=0;k<9;k++){
            float rw=d_AW[k]*RSTv, rh=d_AH[k]*RSTv;
            float mw=fminf(tw,rw), mh=fminf(th,rh);
            float inter=(mw>0.f && mh>0.f)? mw*mh : 0.f;
            float aiou = inter/(at + rw*rh - inter);
            if (aiou > best){ best=aiou; bi=k; }   // first-max = jnp.argmax
        }
        int bn = bi%3;
        bool use = valid && (bi/3 == sid);
        int ii=(int)tx, jj=(int)ty;
        int cc = (bn*F + jj)*F + ii;
        s_code[tid] = use ? (cc | (((int)cl)<<20)) : -1;
        float aw=d_AW[sid*3+bn]*RSTv, ah=d_AH[sid*3+bn]*RSTv;
        s_tv[tid][0]=tx-(float)ii;
        s_tv[tid][1]=ty-(float)jj;
        s_tv[tid][2]=__logf(__fdividef(tw,aw) + 1e-16f);
        s_tv[tid][3]=__logf(__fdividef(th,ah) + 1e-16f);
        s_tv[tid][4]=sqrtf(2.0f - at/(float)FF);
        if (valid){                               // ignore-loop set: order-free OR
            int p = atomicAdd(&s_nbx, 1);
            float htw=0.5f*tw, hth=0.5f*th;
            s_bxc[p]  = make_float4(tx-htw, tx+htw, ty-hth, ty+hth);
            s_at3c[p] = at*(1.0f/3.0f);
        }
        if (use){                                 // target-cell set: existence-only
            int p = atomicAdd(&s_nuse, 1);
            s_used[p] = cc;
        }
    }
    __syncthreads();

    float lxy=0.f, lwh=0.f, lob=0.f, lcl=0.f, l2=0.f;

    if (!tgtblk){
        if (active){
            int nuse = s_nuse, nbx = s_nbx;
            if      (sid==0) cell_compute<0>(a,rembase,nc,cx,cy,cw,chn,co,s_bxc,s_at3c,nbx,s_used,nuse,lob,l2);
            else if (sid==1) cell_compute<1>(a,rembase,nc,cx,cy,cw,chn,co,s_bxc,s_at3c,nbx,s_used,nuse,lob,l2);
            else             cell_compute<2>(a,rembase,nc,cx,cy,cw,chn,co,s_bxc,s_at3c,nbx,s_used,nuse,lob,l2);
        }
    } else {
        if      (sid==0) target_pass<0>(raw,b,tid,s_code,s_tv,lxy,lwh,lob,lcl,l2);
        else if (sid==1) target_pass<1>(raw,b,tid,s_code,s_tv,lxy,lwh,lob,lcl,l2);
        else             target_pass<2>(raw,b,tid,s_code,s_tv,lxy,lwh,lob,lcl,l2);
    }

    // ---- block reduce -> per-component atomics -> last block finalizes ----
    float v0=lxy, v1=lwh, v2=lob, v3=lcl, v4=l2;
    #pragma unroll
    for (int off=32; off>0; off>>=1){
        v0 += __shfl_down(v0, off, 64);
        v1 += __shfl_down(v1, off, 64);
        v2 += __shfl_down(v2, off, 64);
        v3 += __shfl_down(v3, off, 64);
        v4 += __shfl_down(v4, off, 64);
    }
    if ((tid & 63) == 0){
        int w = tid >> 6;
        red[0][w]=v0; red[1][w]=v1; red[2][w]=v2; red[3][w]=v3; red[4][w]=v4;
    }
    __syncthreads();
    if (tid == 0){
        float c0 = red[0][0]+red[0][1]+red[0][2]+red[0][3];
        float c1 = red[1][0]+red[1][1]+red[1][2]+red[1][3];
        float c2 = red[2][0]+red[2][1]+red[2][2]+red[2][3];
        float c3 = red[3][0]+red[3][1]+red[3][2]+red[3][3];
        float c4 = red[4][0]+red[4][1]+red[4][2]+red[4][3];
        atomicAdd(&acc[0*SLOT_STRIDE], c0);
        atomicAdd(&acc[1*SLOT_STRIDE], c1);
        atomicAdd(&acc[2*SLOT_STRIDE], c2);
        atomicAdd(&acc[3*SLOT_STRIDE], c3);
        atomicAdd(&acc[4*SLOT_STRIDE], c4);
        __threadfence();                      // component atomics complete before count
        unsigned old = atomicAdd(cnt, 1u);
        if (old == TOTAL_BLOCKS-1){           // last finisher: coherent read + clear
            float t1 = atomicExch(&acc[0*SLOT_STRIDE], 0.f);
            float t2 = atomicExch(&acc[1*SLOT_STRIDE], 0.f);
            float t3 = atomicExch(&acc[2*SLOT_STRIDE], 0.f);
            float t4 = atomicExch(&acc[3*SLOT_STRIDE], 0.f);
            float t5 = atomicExch(&acc[4*SLOT_STRIDE], 0.f);
            out[0]=t1+t2+t3+t4;
            out[1]=t1; out[2]=t2; out[3]=t3; out[4]=t4; out[5]=t5;
        }
    }
}

extern "C" void kernel_launch(void* const* d_in, const int* in_sizes, int n_in,
                              void* d_out, int out_size, void* d_ws, size_t ws_size,
                              hipStream_t stream) {
    const float* x0     = (const float*)d_in[0];
    const float* x1     = (const float*)d_in[1];
    const float* x2     = (const float*)d_in[2];
    const float* labels = (const float*)d_in[3];
    float* out = (float*)d_out;

    float*    acc = (float*)d_ws;                      // 5 slots, 256 B apart
    unsigned* cnt = (unsigned*)((char*)d_ws + 5*256);  // completion counter

    // bootstrap accumulators+counter past the 0xAA poison (graph memset node)
    hipMemsetAsync(d_ws, 0, 6*256, stream);

    fused_kernel<<<dim3(NBX, BB), 256, 0, stream>>>(x0, x1, x2, labels, acc, cnt, out);
}

// Round 7
// 23.437 us; speedup vs baseline: 1.3519x; 1.3519x over previous
//
#include <hip/hip_runtime.h>

#define BB 16
#define NL 60
#define NA 3
#define NC 80
#define BS 512

// blocks per batch: 9(s0)+3(s1)+1(s2) cell blocks (4 cells/thread, 512 thr) + 1 target
#define NBX0C 9
#define NBX1C 3
#define NBX2C 1
#define NBXC  (NBX0C+NBX1C+NBX2C)   // 13
#define NBX   (NBXC+1)              // 14
#define TOTAL_BLOCKS (NBX*BB)       // 224

__device__ __constant__ float d_AW[9] = {12.f,19.f,40.f,36.f,76.f,72.f,142.f,192.f,459.f};
__device__ __constant__ float d_AH[9] = {16.f,36.f,28.f,75.f,55.f,146.f,110.f,243.f,401.f};

__device__ __forceinline__ float sig_pos(float v){ return __fdividef(1.0f, 1.0f + __expf(-v)); }
__device__ __forceinline__ float sig_neg(float v){ return __fdividef(1.0f, 1.0f + __expf(v)); }
__device__ __forceinline__ float bcef(float p, float t){
    float lp  = __logf(fmaxf(p, 1e-12f));
    float l1p = __logf(1.0f - fminf(p, 1.0f - 1e-7f));
    return -(t*lp + (1.0f - t)*l1p);
}

// ---- issue the channel loads EARLY (before prep+barrier) ----
template<int SID>
__device__ __forceinline__ bool cell_load(const float* __restrict__ raw, int xoff, int b, int tid,
        int &a, int &rembase, int &nc,
        float (&cx)[4], float (&cy)[4], float (&cw)[4], float (&ch)[4], float (&co)[4])
{
    constexpr int F  = (SID==0)?76:(SID==1)?38:19;
    constexpr int FF = F*F;
    int t = xoff*BS + tid;
    if (SID < 2){
        constexpr int NT = 3*FF/4;           // FF divisible by 4 for s0/s1
        if (t >= NT) return false;
        a = t / (FF/4);
        rembase = 4*t - a*FF;
        nc = 4;
        const float* base = raw + ((size_t)(b*(NA*85) + a*85))*FF + rembase;
        float4 q0 = *reinterpret_cast<const float4*>(base);
        float4 q1 = *reinterpret_cast<const float4*>(base +   (size_t)FF);
        float4 q2 = *reinterpret_cast<const float4*>(base + 2*(size_t)FF);
        float4 q3 = *reinterpret_cast<const float4*>(base + 3*(size_t)FF);
        float4 q4 = *reinterpret_cast<const float4*>(base + 4*(size_t)FF);
        cx[0]=q0.x; cx[1]=q0.y; cx[2]=q0.z; cx[3]=q0.w;
        cy[0]=q1.x; cy[1]=q1.y; cy[2]=q1.z; cy[3]=q1.w;
        cw[0]=q2.x; cw[1]=q2.y; cw[2]=q2.z; cw[3]=q2.w;
        ch[0]=q3.x; ch[1]=q3.y; ch[2]=q3.z; ch[3]=q3.w;
        co[0]=q4.x; co[1]=q4.y; co[2]=q4.z; co[3]=q4.w;
    } else {
        constexpr int GPA = (FF+3)/4;        // 91 groups per anchor (361 cells)
        if (t >= 3*GPA) return false;
        a = t / GPA;
        int k = t - a*GPA;
        rembase = 4*k;
        nc = (FF - rembase < 4) ? (FF - rembase) : 4;
        const float* base = raw + ((size_t)(b*(NA*85) + a*85))*FF + rembase;
        #pragma unroll
        for (int c=0;c<4;c++){
            bool v = c < nc;
            cx[c] = v ? base[c]              : 0.f;
            cy[c] = v ? base[(size_t)FF+c]   : 0.f;
            cw[c] = v ? base[2*(size_t)FF+c] : 0.f;
            ch[c] = v ? base[3*(size_t)FF+c] : 0.f;
            co[c] = v ? base[4*(size_t)FF+c] : 0.f;
        }
    }
    return true;
}

template<int SID>
__device__ __forceinline__ void cell_compute(int a, int rembase, int nc,
        const float (&cx)[4], const float (&cy)[4], const float (&cw)[4],
        const float (&ch)[4], const float (&co)[4],
        const float4* s_bxc, const float* s_at3c, int nbx,
        const int* s_used, int nuse,
        float &lob, float &l2)
{
    constexpr int   F   = (SID==0)?76:(SID==1)?38:19;
    constexpr int   FF  = F*F;
    constexpr float RST = (SID==0)?0.125f:(SID==1)?0.0625f:0.03125f;
    float aw = d_AW[SID*3+a]*RST, ah = d_AH[SID*3+a]*RST;
    float plox[4],phix[4],ploy[4],phiy[4],ap3[4];
    #pragma unroll
    for (int c=0;c<4;c++){
        int cel = rembase + c;
        int j = cel / F;                 // compile-time divisor
        int i = cel - j*F;
        float x = sig_pos(cx[c]), y = sig_pos(cy[c]);
        float pw = __expf(cw[c])*aw, ph = __expf(ch[c])*ah;
        float px = x + (float)i, py = y + (float)j;
        float hx = 0.5f*pw, hy = 0.5f*ph;
        plox[c]=px-hx; phix[c]=px+hx; ploy[c]=py-hy; phiy[c]=py+hy;
        ap3[c]=pw*ph*(1.0f/3.0f);
    }
    bool skip0=false, skip1=false, skip2=false, skip3=false;
    #pragma unroll 2
    for (int l=0;l<nbx;l++){             // compacted: valid labels only
        float4 bb = s_bxc[l];
        float thr = s_at3c[l];
        float iw0 = fminf(phix[0],bb.y)-fmaxf(plox[0],bb.x);
        float ih0 = fminf(phiy[0],bb.w)-fmaxf(ploy[0],bb.z);
        float iw1 = fminf(phix[1],bb.y)-fmaxf(plox[1],bb.x);
        float ih1 = fminf(phiy[1],bb.w)-fmaxf(ploy[1],bb.z);
        float iw2 = fminf(phix[2],bb.y)-fmaxf(plox[2],bb.x);
        float ih2 = fminf(phiy[2],bb.w)-fmaxf(ploy[2],bb.z);
        float iw3 = fminf(phix[3],bb.y)-fmaxf(plox[3],bb.x);
        float ih3 = fminf(phiy[3],bb.w)-fmaxf(ploy[3],bb.z);
        skip0 = skip0 || (fmaxf(iw0,0.f)*fmaxf(ih0,0.f) > ap3[0]+thr);
        skip1 = skip1 || (fmaxf(iw1,0.f)*fmaxf(ih1,0.f) > ap3[1]+thr);
        skip2 = skip2 || (fmaxf(iw2,0.f)*fmaxf(ih2,0.f) > ap3[2]+thr);
        skip3 = skip3 || (fmaxf(iw3,0.f)*fmaxf(ih3,0.f) > ap3[3]+thr);
    }
    int cellbase = a*FF + rembase;
    for (int k=0;k<nuse;k++){
        int uc = s_used[k];
        skip0 = skip0 || (uc==cellbase);
        skip1 = skip1 || (uc==cellbase+1);
        skip2 = skip2 || (uc==cellbase+2);
        skip3 = skip3 || (uc==cellbase+3);
    }
    #pragma unroll
    for (int c=0;c<4;c++){
        bool sk = (c==0)?skip0:(c==1)?skip1:(c==2)?skip2:skip3;
        if (c < nc && !sk){
            float snb = sig_neg(co[c]);
            lob += -__logf(fmaxf(snb,1e-7f));
            float ob = 1.0f - snb;
            l2 += ob*ob;
        }
    }
}

__global__ __launch_bounds__(BS) void fused_kernel(
        const float* __restrict__ x0, const float* __restrict__ x1,
        const float* __restrict__ x2, const float* __restrict__ labels,
        float* __restrict__ part)
{
    __shared__ float4 s_bxc[NL];        // cell blocks: compacted valid boxes
    __shared__ float  s_at3c[NL];
    __shared__ int    s_used[NL];
    __shared__ int    s_nuse, s_nbx;
    __shared__ int    s_code3[3][NL];   // target block: rr | aa<<18 | cls<<20
    __shared__ float  s_tv3[3][NL][5];
    __shared__ float  red[5][8];

    const int tid = threadIdx.x;
    const int bxi = blockIdx.x;
    const int b   = blockIdx.y;

    int sid, xoff, tgtblk;
    if      (bxi < NBX0C)       { sid = 0; xoff = bxi;               tgtblk = 0; }
    else if (bxi < NBX0C+NBX1C) { sid = 1; xoff = bxi-NBX0C;         tgtblk = 0; }
    else if (bxi < NBXC)        { sid = 2; xoff = bxi-(NBX0C+NBX1C); tgtblk = 0; }
    else                        { sid = 0; xoff = 0;                 tgtblk = 1; }

    // ---- issue cell loads before prep so latency hides under prep+barrier ----
    float cx[4],cy[4],cw[4],chn[4],co[4];
    int a=0, rembase=0, nc=0;
    bool active=false;
    if (!tgtblk){
        const float* raw = (sid==0)?x0:(sid==1)?x1:x2;
        if      (sid==0) active = cell_load<0>(raw,xoff,b,tid,a,rembase,nc,cx,cy,cw,chn,co);
        else if (sid==1) active = cell_load<1>(raw,xoff,b,tid,a,rembase,nc,cx,cy,cw,chn,co);
        else             active = cell_load<2>(raw,xoff,b,tid,a,rembase,nc,cx,cy,cw,chn,co);
    }

    if (tid == 0){ s_nuse = 0; s_nbx = 0; }
    __syncthreads();

    if (!tgtblk){
        // ---- cell-block prep: compacted boxes + used-cell list (own scale) ----
        if (tid < NL){
            const float RSTv = (sid==0)?0.125f:(sid==1)?0.0625f:0.03125f;
            const int   F    = (sid==0)?76:(sid==1)?38:19;
            const float* lb = labels + ((size_t)b*NL + tid)*5;
            float x1f=lb[0], y1f=lb[1], x2f=lb[2], y2f=lb[3], cl=lb[4];
            bool valid = (x1f+y1f+x2f+y2f+cl) > 0.0f;
            float tx=(x1f+x2f)*0.5f*RSTv, ty=(y1f+y2f)*0.5f*RSTv;
            float tw=(x2f-x1f)*RSTv, th=(y2f-y1f)*RSTv;
            float at=tw*th;
            float best=-1.0f; int bi=0;
            #pragma unroll
            for (int k=0;k<9;k++){
                float rw=d_AW[k]*RSTv, rh=d_AH[k]*RSTv;
                float mw=fminf(tw,rw), mh=fminf(th,rh);
                float inter=(mw>0.f && mh>0.f)? mw*mh : 0.f;
                float aiou = inter/(at + rw*rh - inter);
                if (aiou > best){ best=aiou; bi=k; }   // first-max = jnp.argmax
            }
            if (valid){
                int p = atomicAdd(&s_nbx, 1);
                float htw=0.5f*tw, hth=0.5f*th;
                s_bxc[p]  = make_float4(tx-htw, tx+htw, ty-hth, ty+hth);
                s_at3c[p] = at*(1.0f/3.0f);
            }
            if (valid && (bi/3 == sid)){
                int bn = bi%3;
                int ii=(int)tx, jj=(int)ty;
                int p = atomicAdd(&s_nuse, 1);
                s_used[p] = (bn*F + jj)*F + ii;       // existence-only
            }
        }
    } else {
        // ---- target-block prep: codes + t-values for ALL 3 scales ----
        if (tid < 3*NL){
            int sd = tid/NL, l = tid - sd*NL;
            const float RSTv = (sd==0)?0.125f:(sd==1)?0.0625f:0.03125f;
            const int   F    = (sd==0)?76:(sd==1)?38:19;
            const int   FF   = F*F;
            const float* lb = labels + ((size_t)b*NL + l)*5;
            float x1f=lb[0], y1f=lb[1], x2f=lb[2], y2f=lb[3], cl=lb[4];
            bool valid = (x1f+y1f+x2f+y2f+cl) > 0.0f;
            float tx=(x1f+x2f)*0.5f*RSTv, ty=(y1f+y2f)*0.5f*RSTv;
            float tw=(x2f-x1f)*RSTv, th=(y2f-y1f)*RSTv;
            float at=tw*th;
            float best=-1.0f; int bi=0;
            #pragma unroll
            for (int k=0;k<9;k++){
                float rw=d_AW[k]*RSTv, rh=d_AH[k]*RSTv;
                float mw=fminf(tw,rw), mh=fminf(th,rh);
                float inter=(mw>0.f && mh>0.f)? mw*mh : 0.f;
                float aiou = inter/(at + rw*rh - inter);
                if (aiou > best){ best=aiou; bi=k; }
            }
            int bn = bi%3;
            bool use = valid && (bi/3 == sd);
            int ii=(int)tx, jj=(int)ty;
            int rr = jj*F + ii;                       // in-anchor cell
            s_code3[sd][l] = use ? (rr | (bn<<18) | (((int)cl)<<20)) : -1;
            float aw=d_AW[sd*3+bn]*RSTv, ah=d_AH[sd*3+bn]*RSTv;
            s_tv3[sd][l][0]=tx-(float)ii;
            s_tv3[sd][l][1]=ty-(float)jj;
            s_tv3[sd][l][2]=__logf(__fdividef(tw,aw) + 1e-16f);
            s_tv3[sd][l][3]=__logf(__fdividef(th,ah) + 1e-16f);
            s_tv3[sd][l][4]=sqrtf(2.0f - at/(float)FF);
        }
    }
    __syncthreads();

    float lxy=0.f, lwh=0.f, lob=0.f, lcl=0.f, l2=0.f;

    if (!tgtblk){
        if (active){
            int nuse = s_nuse, nbx = s_nbx;
            if      (sid==0) cell_compute<0>(a,rembase,nc,cx,cy,cw,chn,co,s_bxc,s_at3c,nbx,s_used,nuse,lob,l2);
            else if (sid==1) cell_compute<1>(a,rembase,nc,cx,cy,cw,chn,co,s_bxc,s_at3c,nbx,s_used,nuse,lob,l2);
            else             cell_compute<2>(a,rembase,nc,cx,cy,cw,chn,co,s_bxc,s_at3c,nbx,s_used,nuse,lob,l2);
        }
    } else {
        // ---- merged target pass: all 3 scales, 8 waves ----
        const int wv = tid>>6, lane = tid&63;
        for (int sd=0; sd<3; sd++){
            const float* raw = (sd==0)?x0:(sd==1)?x1:x2;
            const int F  = (sd==0)?76:(sd==1)?38:19;
            const int FF = F*F;
            int mycode = (lane < NL) ? s_code3[sd][lane] : -1;
            for (int l=wv; l<NL; l+=8){              // wave-uniform l
                int cd = s_code3[sd][l];
                if (cd < 0) continue;
                int tcell = cd & 0xFFFFF;            // rr | aa<<18
                bool match = (mycode >= 0) && ((mycode & 0xFFFFF) == tcell);
                unsigned long long mask = __ballot(match);
                int last = 63 - __clzll(mask);
                if (last != l) continue;             // single owner per cell
                unsigned long long cm0=0ull, cm1=0ull, mm=mask;
                while (mm){
                    int q = __ffsll((unsigned long long)mm) - 1;
                    mm &= mm - 1;
                    int cc = s_code3[sd][q] >> 20;
                    if (cc < 64) cm0 |= 1ull<<cc; else cm1 |= 1ull<<(cc-64);
                }
                int aa = (cd>>18)&3, rr = cd & 0x3FFFF;
                const float* cb = raw + ((size_t)(b*(NA*85) + aa*85))*FF + rr;
                float p1l = cb[(size_t)(5+lane)*FF];
                float p2l = (lane < 16) ? cb[(size_t)(69+lane)*FF] : 0.f;
                float e0=0.f,e1=0.f,e2=0.f,e3=0.f,e4=0.f;
                if (lane == 0){ e0=cb[0]; e1=cb[(size_t)FF]; e2=cb[2*(size_t)FF];
                                e3=cb[3*(size_t)FF]; e4=cb[4*(size_t)FF]; }
                float p1 = sig_pos(p1l);
                float t1v = (((cm0>>lane)&1ull)!=0ull) ? 1.f : 0.f;
                lcl += bcef(p1, t1v);
                float d1 = p1 - t1v; l2 += d1*d1;
                if (lane < 16){
                    float p2 = sig_pos(p2l);
                    float t2v = (((cm1>>lane)&1ull)!=0ull) ? 1.f : 0.f;
                    lcl += bcef(p2, t2v);
                    float d2 = p2 - t2v; l2 += d2*d2;
                }
                if (lane == 0){
                    float xx=sig_pos(e0), yy=sig_pos(e1), ob=sig_pos(e4);
                    float t0=s_tv3[sd][l][0], t1=s_tv3[sd][l][1], t2=s_tv3[sd][l][2],
                          t3=s_tv3[sd][l][3], sc=s_tv3[sd][l][4];
                    lxy += sc*sc*(bcef(xx,t0)+bcef(yy,t1));
                    float d0=(e2-t2)*sc, dd=(e3-t3)*sc;
                    lwh += 0.5f*(d0*d0+dd*dd);
                    lob += -__logf(fmaxf(ob,1e-12f));
                    float dx=xx-t0, dy=yy-t1, dob=ob-1.f;
                    l2  += dx*dx+dy*dy+d0*d0+dd*dd+dob*dob;
                }
            }
        }
    }

    // ---- block reduce (8 waves) -> plain store of this block's 5 partials ----
    float v0=lxy, v1=lwh, v2=lob, v3=lcl, v4=l2;
    #pragma unroll
    for (int off=32; off>0; off>>=1){
        v0 += __shfl_down(v0, off, 64);
        v1 += __shfl_down(v1, off, 64);
        v2 += __shfl_down(v2, off, 64);
        v3 += __shfl_down(v3, off, 64);
        v4 += __shfl_down(v4, off, 64);
    }
    if ((tid & 63) == 0){
        int w = tid >> 6;
        red[0][w]=v0; red[1][w]=v1; red[2][w]=v2; red[3][w]=v3; red[4][w]=v4;
    }
    __syncthreads();
    if (tid == 0){
        int slot = b*NBX + bxi;
        #pragma unroll
        for (int c=0;c<5;c++){
            part[c*TOTAL_BLOCKS + slot] = red[c][0]+red[c][1]+red[c][2]+red[c][3]
                                        + red[c][4]+red[c][5]+red[c][6]+red[c][7];
        }
    }
}

// ---------------- final reduction: 224 partials x 5 comps (kernel boundary = coherence) ----
__global__ __launch_bounds__(256) void fin_kernel(const float* __restrict__ part,
                                                  float* __restrict__ out)
{
    __shared__ double red[5][4];
    int tid = threadIdx.x;
    double v[5] = {0,0,0,0,0};
    if (tid < TOTAL_BLOCKS){
        #pragma unroll
        for (int c=0;c<5;c++) v[c] = (double)part[c*TOTAL_BLOCKS + tid];
    }
    #pragma unroll
    for (int off=32; off>0; off>>=1){
        #pragma unroll
        for (int c=0;c<5;c++) v[c] += __shfl_down(v[c], off, 64);
    }
    if ((tid & 63) == 0){
        int w = tid >> 6;
        #pragma unroll
        for (int c=0;c<5;c++) red[c][w] = v[c];
    }
    __syncthreads();
    if (tid == 0){
        double lxy = red[0][0]+red[0][1]+red[0][2]+red[0][3];
        double lwh = red[1][0]+red[1][1]+red[1][2]+red[1][3];
        double lob = red[2][0]+red[2][1]+red[2][2]+red[2][3];
        double lcl = red[3][0]+red[3][1]+red[3][2]+red[3][3];
        double l2  = red[4][0]+red[4][1]+red[4][2]+red[4][3];
        out[0]=(float)(lxy+lwh+lob+lcl);
        out[1]=(float)lxy; out[2]=(float)lwh; out[3]=(float)lob;
        out[4]=(float)lcl; out[5]=(float)l2;
    }
}

extern "C" void kernel_launch(void* const* d_in, const int* in_sizes, int n_in,
                              void* d_out, int out_size, void* d_ws, size_t ws_size,
                              hipStream_t stream) {
    const float* x0     = (const float*)d_in[0];
    const float* x1     = (const float*)d_in[1];
    const float* x2     = (const float*)d_in[2];
    const float* labels = (const float*)d_in[3];
    float* out = (float*)d_out;

    float* part = (float*)d_ws;   // 5*224*4 = 4480 B, plain-stored each call

    fused_kernel<<<dim3(NBX, BB), BS, 0, stream>>>(x0, x1, x2, labels, part);
    fin_kernel<<<1, 256, 0, stream>>>(part, out);
}